// Round 1
// baseline (601.367 us; speedup 1.0000x reference)
//
#include <hip/hip_runtime.h>

// MultiHeadFullAttention: B=2, T=2048, D=1024, H=16, dh=64, causal.
// Pipeline: fp32->bf16 prep -> 3 proj GEMMs (MFMA) -> flash attention -> out GEMM.
// All intermediates bf16 in d_ws (64 MiB needed). attn_mask input unused (pure causal).

typedef __attribute__((ext_vector_type(8))) __bf16 bf16x8;
typedef __attribute__((ext_vector_type(4))) float f32x4;

constexpr int BATCH  = 2;
constexpr int TSEQ   = 2048;
constexpr int DMODEL = 1024;
constexpr int NHEAD  = 16;
constexpr int DHEAD  = 64;
constexpr int MROWS  = BATCH * TSEQ;  // 4096

static __device__ __forceinline__ unsigned short f2bf(float f) {
  union { float f; unsigned int u; } v; v.f = f;
  unsigned int u = v.u;
  return (unsigned short)((u + 0x7fffu + ((u >> 16) & 1u)) >> 16);
}

__global__ __launch_bounds__(256) void cvt_kernel(const float* __restrict__ src,
                                                  unsigned short* __restrict__ dst,
                                                  int n4) {
  int i = blockIdx.x * 256 + threadIdx.x;
  if (i >= n4) return;
  float4 f = ((const float4*)src)[i];
  ushort4 o;
  o.x = f2bf(f.x); o.y = f2bf(f.y); o.z = f2bf(f.z); o.w = f2bf(f.w);
  ((ushort4*)dst)[i] = o;
}

// C[m][n] = sum_k X[m][k] * W[n][k] + bias[n]   (nn.Linear: x @ W^T + b)
// K = DMODEL = 1024. Block: 4 waves, 64(M) x 64(N) tile; wave w -> rows 16w..16w+15.
// MODE 0: store bf16 to [B,H,T,dh] (Q,K)   MODE 1: store bf16 to [B,H,dh,T] (V^T)
// MODE 2: store fp32 to [M,N] (final output)
template <int MODE>
__global__ __launch_bounds__(256) void gemm_bt(const unsigned short* __restrict__ X,
                                               const unsigned short* __restrict__ W,
                                               const float* __restrict__ bias,
                                               void* __restrict__ outp) {
  constexpr int K = DMODEL;
  const int lane = threadIdx.x & 63;
  const int wave = threadIdx.x >> 6;
  const int l16  = lane & 15;
  const int lk   = lane >> 4;
  const int row0 = blockIdx.x * 64 + wave * 16;
  const int col0 = blockIdx.y * 64;

  const unsigned short* xp = X + (size_t)(row0 + l16) * K + lk * 8;
  const unsigned short* wp = W + (size_t)(col0 + l16) * K + lk * 8;

  f32x4 acc[4];
#pragma unroll
  for (int nt = 0; nt < 4; ++nt) acc[nt] = (f32x4){0.f, 0.f, 0.f, 0.f};

  for (int k0 = 0; k0 < K; k0 += 32) {
    bf16x8 a = *(const bf16x8*)(xp + k0);
#pragma unroll
    for (int nt = 0; nt < 4; ++nt) {
      bf16x8 b = *(const bf16x8*)(wp + (size_t)nt * 16 * K + k0);
      acc[nt] = __builtin_amdgcn_mfma_f32_16x16x32_bf16(a, b, acc[nt], 0, 0, 0);
    }
  }

#pragma unroll
  for (int nt = 0; nt < 4; ++nt) {
#pragma unroll
    for (int r = 0; r < 4; ++r) {
      int m = row0 + 4 * lk + r;       // D layout: row = 4*(lane>>4)+reg
      int n = col0 + nt * 16 + l16;    //           col = lane&15 (+16*nt)
      float v = acc[nt][r] + bias[n];
      if (MODE == 2) {
        ((float*)outp)[(size_t)m * DMODEL + n] = v;
      } else {
        int b = m >> 11, t = m & (TSEQ - 1);
        int h = n >> 6, dd = n & (DHEAD - 1);
        size_t idx;
        if (MODE == 0) idx = (((size_t)(b * NHEAD + h)) * TSEQ + t) * DHEAD + dd;
        else           idx = (((size_t)(b * NHEAD + h)) * DHEAD + dd) * TSEQ + t;
        ((unsigned short*)outp)[idx] = f2bf(v);
      }
    }
  }
}

// Flash attention, causal. grid.x = T/64 (q-tile), grid.y = B*H.
// Q,K in [B,H,T,dh] bf16; V in [B,H,dh,T] bf16 (transposed). Out: [B,T,D] bf16.
__global__ __launch_bounds__(256) void flash_attn(const unsigned short* __restrict__ Qh,
                                                  const unsigned short* __restrict__ Kh,
                                                  const unsigned short* __restrict__ Vt,
                                                  unsigned short* __restrict__ AO) {
  const int lane = threadIdx.x & 63;
  const int wave = threadIdx.x >> 6;
  const int l16  = lane & 15;
  const int lk   = lane >> 4;
  const int q0   = blockIdx.x * 64;
  const int bh   = blockIdx.y;
  const int b    = bh >> 4, h = bh & 15;

  const unsigned short* Qb = Qh + (size_t)bh * TSEQ * DHEAD;
  const unsigned short* Kb = Kh + (size_t)bh * TSEQ * DHEAD;
  const unsigned short* Vb = Vt + (size_t)bh * DHEAD * TSEQ;

  __shared__ __align__(16) unsigned short plds[4][16][72];  // +8 pad: bank spread

  bf16x8 qf[2];
  {
    const unsigned short* qp = Qb + (size_t)(q0 + wave * 16 + l16) * DHEAD + lk * 8;
    qf[0] = *(const bf16x8*)(qp);
    qf[1] = *(const bf16x8*)(qp + 32);
  }

  float mrow[4], lrow[4];
  f32x4 acco[4];
#pragma unroll
  for (int r = 0; r < 4; ++r) { mrow[r] = -1e30f; lrow[r] = 0.f; }
#pragma unroll
  for (int dt = 0; dt < 4; ++dt) acco[dt] = (f32x4){0.f, 0.f, 0.f, 0.f};

  const int qrow_base = q0 + wave * 16 + 4 * lk;
  const int nkb = blockIdx.x + 1;  // causal: K-blocks 0 .. q0/64

  for (int kb = 0; kb < nkb; ++kb) {
    const int kbase = kb * 64;
    f32x4 s[4];
#pragma unroll
    for (int nt = 0; nt < 4; ++nt) {
      const unsigned short* kp = Kb + (size_t)(kbase + nt * 16 + l16) * DHEAD + lk * 8;
      bf16x8 k0f = *(const bf16x8*)(kp);
      bf16x8 k1f = *(const bf16x8*)(kp + 32);
      f32x4 z = (f32x4){0.f, 0.f, 0.f, 0.f};
      z = __builtin_amdgcn_mfma_f32_16x16x32_bf16(qf[0], k0f, z, 0, 0, 0);
      z = __builtin_amdgcn_mfma_f32_16x16x32_bf16(qf[1], k1f, z, 0, 0, 0);
      s[nt] = z;
    }
    // online softmax (rows live in 16-lane groups; 4 rows per lane as regs 0..3)
#pragma unroll
    for (int r = 0; r < 4; ++r) {
      const int qrow = qrow_base + r;
      float mx = -1e30f;
#pragma unroll
      for (int nt = 0; nt < 4; ++nt) {
        float v = s[nt][r] * 0.125f;  // 1/sqrt(64)
        int kcol = kbase + nt * 16 + l16;
        v = (kcol <= qrow) ? v : -1e30f;
        s[nt][r] = v;
        mx = fmaxf(mx, v);
      }
#pragma unroll
      for (int off = 1; off < 16; off <<= 1) mx = fmaxf(mx, __shfl_xor(mx, off, 16));
      float mnew = fmaxf(mrow[r], mx);
      float alpha = __expf(mrow[r] - mnew);
      float rs = 0.f;
#pragma unroll
      for (int nt = 0; nt < 4; ++nt) {
        float p = __expf(s[nt][r] - mnew);
        s[nt][r] = p;
        rs += p;
      }
#pragma unroll
      for (int off = 1; off < 16; off <<= 1) rs += __shfl_xor(rs, off, 16);
      lrow[r] = lrow[r] * alpha + rs;
      mrow[r] = mnew;
#pragma unroll
      for (int dt = 0; dt < 4; ++dt) acco[dt][r] *= alpha;
    }
    // P (D-layout) -> LDS -> A-fragment layout for PV
#pragma unroll
    for (int nt = 0; nt < 4; ++nt)
#pragma unroll
      for (int r = 0; r < 4; ++r)
        plds[wave][4 * lk + r][nt * 16 + l16] = f2bf(s[nt][r]);
    __syncthreads();
    bf16x8 pf0 = *(const bf16x8*)&plds[wave][l16][lk * 8];
    bf16x8 pf1 = *(const bf16x8*)&plds[wave][l16][32 + lk * 8];
#pragma unroll
    for (int dt = 0; dt < 4; ++dt) {
      const unsigned short* vp = Vb + (size_t)(dt * 16 + l16) * TSEQ + kbase + lk * 8;
      bf16x8 v0 = *(const bf16x8*)(vp);
      bf16x8 v1 = *(const bf16x8*)(vp + 32);
      acco[dt] = __builtin_amdgcn_mfma_f32_16x16x32_bf16(pf0, v0, acco[dt], 0, 0, 0);
      acco[dt] = __builtin_amdgcn_mfma_f32_16x16x32_bf16(pf1, v1, acco[dt], 0, 0, 0);
    }
    __syncthreads();
  }

#pragma unroll
  for (int dt = 0; dt < 4; ++dt)
#pragma unroll
    for (int r = 0; r < 4; ++r) {
      int t = qrow_base + r;
      int col = h * DHEAD + dt * 16 + l16;
      float v = acco[dt][r] / lrow[r];
      AO[((size_t)(b * TSEQ + t)) * DMODEL + col] = f2bf(v);
    }
}

extern "C" void kernel_launch(void* const* d_in, const int* in_sizes, int n_in,
                              void* d_out, int out_size, void* d_ws, size_t ws_size,
                              hipStream_t stream) {
  const float* x_q = (const float*)d_in[0];
  const float* x_k = (const float*)d_in[1];
  const float* x_v = (const float*)d_in[2];
  // d_in[3] = attn_mask (pure causal, recomputed analytically)
  const float* Wq = (const float*)d_in[4];
  const float* bq = (const float*)d_in[5];
  const float* Wk = (const float*)d_in[6];
  const float* bk = (const float*)d_in[7];
  const float* Wv = (const float*)d_in[8];
  const float* bv = (const float*)d_in[9];
  const float* Wo = (const float*)d_in[10];
  const float* bo = (const float*)d_in[11];
  // d_in[12] = n_heads (=16, hardcoded)

  const size_t nx = (size_t)MROWS * DMODEL;   // 4 Mi elems
  const size_t nw = (size_t)DMODEL * DMODEL;  // 1 Mi elems
  unsigned short* ws   = (unsigned short*)d_ws;
  unsigned short* xq_b = ws;
  unsigned short* xk_b = xq_b + nx;
  unsigned short* xv_b = xk_b + nx;
  unsigned short* wq_b = xv_b + nx;
  unsigned short* wk_b = wq_b + nw;
  unsigned short* wv_b = wk_b + nw;
  unsigned short* wo_b = wv_b + nw;
  unsigned short* Qh   = wo_b + nw;
  unsigned short* Kh   = Qh + nx;
  unsigned short* Vt   = Kh + nx;
  unsigned short* AO   = Vt + nx;  // total 64 MiB

  const int n4x = (int)(nx / 4), n4w = (int)(nw / 4);
  cvt_kernel<<<(n4x + 255) / 256, 256, 0, stream>>>(x_q, xq_b, n4x);
  cvt_kernel<<<(n4x + 255) / 256, 256, 0, stream>>>(x_k, xk_b, n4x);
  cvt_kernel<<<(n4x + 255) / 256, 256, 0, stream>>>(x_v, xv_b, n4x);
  cvt_kernel<<<(n4w + 255) / 256, 256, 0, stream>>>(Wq, wq_b, n4w);
  cvt_kernel<<<(n4w + 255) / 256, 256, 0, stream>>>(Wk, wk_b, n4w);
  cvt_kernel<<<(n4w + 255) / 256, 256, 0, stream>>>(Wv, wv_b, n4w);
  cvt_kernel<<<(n4w + 255) / 256, 256, 0, stream>>>(Wo, wo_b, n4w);

  dim3 gg(MROWS / 64, DMODEL / 64);
  gemm_bt<0><<<gg, 256, 0, stream>>>(xq_b, wq_b, bq, Qh);
  gemm_bt<0><<<gg, 256, 0, stream>>>(xk_b, wk_b, bk, Kh);
  gemm_bt<1><<<gg, 256, 0, stream>>>(xv_b, wv_b, bv, Vt);

  flash_attn<<<dim3(TSEQ / 64, BATCH * NHEAD), 256, 0, stream>>>(Qh, Kh, Vt, AO);

  gemm_bt<2><<<gg, 256, 0, stream>>>(AO, wo_b, bo, d_out);
}

// Round 3
// 175.933 us; speedup vs baseline: 3.4182x; 3.4182x over previous
//
#include <hip/hip_runtime.h>

// MultiHeadFullAttention: B=2, T=2048, D=1024, H=16, dh=64, causal.
// fp32->bf16 cvt (2 launches) -> fused QKV GEMM (MFMA, LDS dbuf) -> flash attn
// (LDS-staged K/V, prefetch) -> output GEMM. attn_mask unused (pure causal).

typedef __attribute__((ext_vector_type(8))) __bf16 bf16x8;
typedef __attribute__((ext_vector_type(4))) float f32x4;
typedef unsigned short u16;

constexpr int BATCH  = 2;
constexpr int TSEQ   = 2048;
constexpr int DMODEL = 1024;
constexpr int NHEAD  = 16;
constexpr int DHEAD  = 64;
constexpr int MROWS  = BATCH * TSEQ;  // 4096

static __device__ __forceinline__ u16 f2bf(float f) {
  union { float f; unsigned int u; } v; v.f = f;
  unsigned int u = v.u;
  return (u16)((u + 0x7fffu + ((u >> 16) & 1u)) >> 16);
}

// async global->LDS, 16B per lane; lds base must be wave-uniform (HW adds lane*16)
static __device__ __forceinline__ void gload16(const void* g, void* l) {
  __builtin_amdgcn_global_load_lds(
      (const __attribute__((address_space(1))) void*)g,
      (__attribute__((address_space(3))) void*)l, 16, 0, 0);
}

__global__ __launch_bounds__(256) void cvt_multi(const float* __restrict__ s0,
                                                 const float* __restrict__ s1,
                                                 const float* __restrict__ s2,
                                                 const float* __restrict__ s3,
                                                 u16* __restrict__ d0, u16* __restrict__ d1,
                                                 u16* __restrict__ d2, u16* __restrict__ d3,
                                                 int n4) {
  const float* s; u16* d;
  switch (blockIdx.y) {
    case 0: s = s0; d = d0; break;
    case 1: s = s1; d = d1; break;
    case 2: s = s2; d = d2; break;
    default: s = s3; d = d3; break;
  }
  int i = blockIdx.x * 256 + threadIdx.x;
  if (i >= n4) return;
  float4 f = ((const float4*)s)[i];
  ushort4 o;
  o.x = f2bf(f.x); o.y = f2bf(f.y); o.z = f2bf(f.z); o.w = f2bf(f.w);
  ((ushort4*)d)[i] = o;
}

// ---------------- GEMM core: C[m][n] = X[m][:] . W[n][:] + bias[n] ----------------
// 512 threads = 8 waves (2x4). Tile 128x128, BK=32. LDS in "fragment order":
// tile byte(row,kslot) = (row>>4)*1024 + kslot*256 + (row&15)*16  -> every
// ds_read_b128 is base + lane*16 (conflict-free) and gload_lds dest is linear.
// Staging: wave w covers site s=w: rows w*16+(lane&15), k-slot lane>>4.
template <typename Epi>
static __device__ __forceinline__ void gemm_body(const u16* __restrict__ X_,
                                                 const u16* __restrict__ W_,
                                                 const float* __restrict__ bias,
                                                 Epi epi) {
  __shared__ __align__(16) u16 As[2][4096];
  __shared__ __align__(16) u16 Bs[2][4096];
  const int lane = threadIdx.x & 63, wave = threadIdx.x >> 6;
  const int l16 = lane & 15, lk = lane >> 4;
  const int wm = wave >> 2, wn = wave & 3;
  const int row0 = blockIdx.x * 128, col0 = blockIdx.y * 128;
  constexpr int K = DMODEL;
  const u16* ga = X_ + (size_t)(row0 + wave * 16 + l16) * K + lk * 8;
  const u16* gb = W_ + (size_t)(col0 + wave * 16 + l16) * K + lk * 8;
  f32x4 acc[4][2];
#pragma unroll
  for (int mt = 0; mt < 4; ++mt)
#pragma unroll
    for (int nt = 0; nt < 2; ++nt) acc[mt][nt] = (f32x4){0.f, 0.f, 0.f, 0.f};
  gload16(ga, &As[0][wave * 512]);
  gload16(gb, &Bs[0][wave * 512]);
  __syncthreads();
  int buf = 0;
  for (int ks = 0; ks < K / 32; ++ks) {
    if (ks + 1 < K / 32) {
      gload16(ga + (ks + 1) * 32, &As[buf ^ 1][wave * 512]);
      gload16(gb + (ks + 1) * 32, &Bs[buf ^ 1][wave * 512]);
    }
    bf16x8 a[4], b[2];
#pragma unroll
    for (int mt = 0; mt < 4; ++mt)
      a[mt] = *(const bf16x8*)&As[buf][(wm * 4 + mt) * 512 + lane * 8];
#pragma unroll
    for (int nt = 0; nt < 2; ++nt)
      b[nt] = *(const bf16x8*)&Bs[buf][(wn * 2 + nt) * 512 + lane * 8];
#pragma unroll
    for (int mt = 0; mt < 4; ++mt)
#pragma unroll
      for (int nt = 0; nt < 2; ++nt)
        acc[mt][nt] =
            __builtin_amdgcn_mfma_f32_16x16x32_bf16(a[mt], b[nt], acc[mt][nt], 0, 0, 0);
    __syncthreads();
    buf ^= 1;
  }
#pragma unroll
  for (int mt = 0; mt < 4; ++mt)
#pragma unroll
    for (int nt = 0; nt < 2; ++nt)
#pragma unroll
      for (int r = 0; r < 4; ++r) {
        int m = row0 + wm * 64 + mt * 16 + lk * 4 + r;
        int n = col0 + wn * 32 + nt * 16 + l16;
        float v = acc[mt][nt][r] + bias[n];
        epi(m, n, v);
      }
}

// z: 0=Q, 1=K (both -> [B,H,T,dh] bf16), 2=V (-> [B,H,dh,T] bf16)
__global__ __launch_bounds__(512) void gemm_qkv(
    const u16* __restrict__ xq, const u16* __restrict__ xk, const u16* __restrict__ xv,
    const u16* __restrict__ wq, const u16* __restrict__ wk, const u16* __restrict__ wv,
    const float* __restrict__ bq, const float* __restrict__ bk, const float* __restrict__ bv,
    u16* __restrict__ Qh, u16* __restrict__ Kh, u16* __restrict__ Vt) {
  const int z = blockIdx.z;
  const u16* X = z == 0 ? xq : (z == 1 ? xk : xv);
  const u16* W = z == 0 ? wq : (z == 1 ? wk : wv);
  const float* bias = z == 0 ? bq : (z == 1 ? bk : bv);
  u16* O01 = z == 0 ? Qh : Kh;
  gemm_body(X, W, bias, [&](int m, int n, float v) {
    int bb = m >> 11, t = m & (TSEQ - 1);
    int h = n >> 6, dd = n & (DHEAD - 1);
    if (z == 2)
      Vt[(((size_t)(bb * NHEAD + h)) * DHEAD + dd) * TSEQ + t] = f2bf(v);
    else
      O01[(((size_t)(bb * NHEAD + h)) * TSEQ + t) * DHEAD + dd] = f2bf(v);
  });
}

__global__ __launch_bounds__(512) void gemm_o(const u16* __restrict__ AO,
                                              const u16* __restrict__ wo,
                                              const float* __restrict__ bias,
                                              float* __restrict__ out) {
  gemm_body(AO, wo, bias,
            [&](int m, int n, float v) { out[(size_t)m * DMODEL + n] = v; });
}

// ---------------- flash attention ----------------
// grid: x = b*H+h (fast), y = q-tile (reversed -> heavy first). 256 thr = 4 waves,
// each wave owns 16 q-rows. K/V tiles (64 wide) double-buffered in LDS, fragment
// order, prefetched one tile ahead. plds is wave-private (no barrier needed).
__global__ __launch_bounds__(256) void flash_attn(const u16* __restrict__ Qh,
                                                  const u16* __restrict__ Kh,
                                                  const u16* __restrict__ Vt,
                                                  u16* __restrict__ AO) {
  const int lane = threadIdx.x & 63, wave = threadIdx.x >> 6;
  const int l16 = lane & 15, lk = lane >> 4;
  const int bh = blockIdx.x;
  const int qt = (gridDim.y - 1) - blockIdx.y;
  const int q0 = qt * 64;
  const int b = bh >> 4, h = bh & 15;

  __shared__ __align__(16) u16 Kl[2][4096];
  __shared__ __align__(16) u16 Vl[2][4096];
  __shared__ __align__(16) u16 plds[4][16][72];

  const u16* Qb = Qh + (size_t)bh * TSEQ * DHEAD;
  const u16* Kb = Kh + (size_t)bh * TSEQ * DHEAD;
  const u16* Vb = Vt + (size_t)bh * DHEAD * TSEQ;

  bf16x8 qf[2];
  {
    const u16* qp = Qb + (size_t)(q0 + wave * 16 + l16) * DHEAD + lk * 8;
    qf[0] = *(const bf16x8*)(qp);
    qf[1] = *(const bf16x8*)(qp + 32);
  }

  float mrow[4], lrow[4];
  f32x4 acco[4];
#pragma unroll
  for (int r = 0; r < 4; ++r) { mrow[r] = -1e30f; lrow[r] = 0.f; }
#pragma unroll
  for (int dt = 0; dt < 4; ++dt) acco[dt] = (f32x4){0.f, 0.f, 0.f, 0.f};

  // staging: site s = j*4+wave (j=0..1); tile rows (s>>1)*16 + l16,
  // k-slot (s&1)*4 + lk; LDS dest = s*512 elems (linear, lane*16B)
  auto stage_kv = [&](int bufi, int kbase) {
#pragma unroll
    for (int j = 0; j < 2; ++j) {
      int s = j * 4 + wave;
      int trow = (s >> 1) * 16 + l16;
      int dhs = (s & 1) * 4 + lk;
      gload16(Kb + (size_t)(kbase + trow) * DHEAD + dhs * 8, &Kl[bufi][s * 512]);
      gload16(Vb + (size_t)trow * TSEQ + kbase + dhs * 8, &Vl[bufi][s * 512]);
    }
  };

  const int nkb = qt + 1;
  stage_kv(0, 0);
  __syncthreads();
  int buf = 0;
  const int qrow_base = q0 + wave * 16 + 4 * lk;

  for (int kb = 0; kb < nkb; ++kb) {
    const int kbase = kb * 64;
    if (kb + 1 < nkb) stage_kv(buf ^ 1, kbase + 64);

    f32x4 s[4];
#pragma unroll
    for (int nt = 0; nt < 4; ++nt) {
      bf16x8 k0f = *(const bf16x8*)&Kl[buf][nt * 1024 + lane * 8];
      bf16x8 k1f = *(const bf16x8*)&Kl[buf][nt * 1024 + 512 + lane * 8];
      f32x4 z = (f32x4){0.f, 0.f, 0.f, 0.f};
      z = __builtin_amdgcn_mfma_f32_16x16x32_bf16(qf[0], k0f, z, 0, 0, 0);
      z = __builtin_amdgcn_mfma_f32_16x16x32_bf16(qf[1], k1f, z, 0, 0, 0);
      s[nt] = z;
    }
#pragma unroll
    for (int r = 0; r < 4; ++r) {
      const int qrow = qrow_base + r;
      float mx = -1e30f;
#pragma unroll
      for (int nt = 0; nt < 4; ++nt) {
        float v = s[nt][r] * 0.125f;  // 1/sqrt(64)
        int kcol = kbase + nt * 16 + l16;
        v = (kcol <= qrow) ? v : -1e30f;
        s[nt][r] = v;
        mx = fmaxf(mx, v);
      }
#pragma unroll
      for (int off = 1; off < 16; off <<= 1) mx = fmaxf(mx, __shfl_xor(mx, off, 16));
      float mnew = fmaxf(mrow[r], mx);
      float alpha = __expf(mrow[r] - mnew);
      float rs = 0.f;
#pragma unroll
      for (int nt = 0; nt < 4; ++nt) {
        float p = __expf(s[nt][r] - mnew);
        s[nt][r] = p;
        rs += p;
      }
#pragma unroll
      for (int off = 1; off < 16; off <<= 1) rs += __shfl_xor(rs, off, 16);
      lrow[r] = lrow[r] * alpha + rs;
      mrow[r] = mnew;
#pragma unroll
      for (int dt = 0; dt < 4; ++dt) acco[dt][r] *= alpha;
    }
    // P (D-layout) -> wave-private LDS -> A-fragment layout (same-wave ordering
    // is handled by compiler lgkmcnt; no barrier needed)
#pragma unroll
    for (int nt = 0; nt < 4; ++nt)
#pragma unroll
      for (int r = 0; r < 4; ++r)
        plds[wave][4 * lk + r][nt * 16 + l16] = f2bf(s[nt][r]);
    bf16x8 pf0 = *(const bf16x8*)&plds[wave][l16][lk * 8];
    bf16x8 pf1 = *(const bf16x8*)&plds[wave][l16][32 + lk * 8];
#pragma unroll
    for (int dt = 0; dt < 4; ++dt) {
      bf16x8 v0 = *(const bf16x8*)&Vl[buf][dt * 1024 + lane * 8];
      bf16x8 v1 = *(const bf16x8*)&Vl[buf][dt * 1024 + 512 + lane * 8];
      acco[dt] = __builtin_amdgcn_mfma_f32_16x16x32_bf16(pf0, v0, acco[dt], 0, 0, 0);
      acco[dt] = __builtin_amdgcn_mfma_f32_16x16x32_bf16(pf1, v1, acco[dt], 0, 0, 0);
    }
    __syncthreads();  // staged buf^1 ready; buf safe to overwrite next iter
    buf ^= 1;
  }

#pragma unroll
  for (int dt = 0; dt < 4; ++dt)
#pragma unroll
    for (int r = 0; r < 4; ++r) {
      int t = qrow_base + r;
      int col = h * DHEAD + dt * 16 + l16;
      float v = acco[dt][r] / lrow[r];
      AO[((size_t)(b * TSEQ + t)) * DMODEL + col] = f2bf(v);
    }
}

extern "C" void kernel_launch(void* const* d_in, const int* in_sizes, int n_in,
                              void* d_out, int out_size, void* d_ws, size_t ws_size,
                              hipStream_t stream) {
  const float* x_q = (const float*)d_in[0];
  const float* x_k = (const float*)d_in[1];
  const float* x_v = (const float*)d_in[2];
  const float* Wq = (const float*)d_in[4];
  const float* bq = (const float*)d_in[5];
  const float* Wk = (const float*)d_in[6];
  const float* bk = (const float*)d_in[7];
  const float* Wv = (const float*)d_in[8];
  const float* bv = (const float*)d_in[9];
  const float* Wo = (const float*)d_in[10];
  const float* bo = (const float*)d_in[11];

  const size_t nx = (size_t)MROWS * DMODEL;
  const size_t nw = (size_t)DMODEL * DMODEL;
  u16* ws   = (u16*)d_ws;
  u16* xq_b = ws;
  u16* xk_b = xq_b + nx;
  u16* xv_b = xk_b + nx;
  u16* wq_b = xv_b + nx;
  u16* wk_b = wq_b + nw;
  u16* wv_b = wk_b + nw;
  u16* wo_b = wv_b + nw;
  u16* Qh   = wo_b + nw;
  u16* Kh   = Qh + nx;
  u16* Vt   = Kh + nx;
  u16* AO   = Vt + nx;  // total 64 MiB

  const int n4x = (int)(nx / 4), n4w = (int)(nw / 4);
  cvt_multi<<<dim3((n4x + 255) / 256, 3), 256, 0, stream>>>(
      x_q, x_k, x_v, nullptr, xq_b, xk_b, xv_b, nullptr, n4x);
  cvt_multi<<<dim3((n4w + 255) / 256, 4), 256, 0, stream>>>(
      Wq, Wk, Wv, Wo, wq_b, wk_b, wv_b, wo_b, n4w);

  gemm_qkv<<<dim3(MROWS / 128, DMODEL / 128, 3), 512, 0, stream>>>(
      xq_b, xk_b, xv_b, wq_b, wk_b, wv_b, bq, bk, bv, Qh, Kh, Vt);

  flash_attn<<<dim3(BATCH * NHEAD, TSEQ / 64), 256, 0, stream>>>(Qh, Kh, Vt, AO);

  gemm_o<<<dim3(MROWS / 128, DMODEL / 128), 512, 0, stream>>>(AO, wo_b, bo, (float*)d_out);
}

// Round 4
// 158.157 us; speedup vs baseline: 3.8023x; 1.1124x over previous
//
#include <hip/hip_runtime.h>

// MultiHeadFullAttention: B=2, T=2048, D=1024, H=16, dh=64, causal.
// fp32->bf16 cvt (2 launches) -> fused QKV GEMM (MFMA, LDS dbuf; 1/8 scale folded
// into Q) -> flash attn (512 thr, 2 q-tiles/block, LDS K/V dbuf, defer-max,
// diagonal-only masking, end-of-loop sum reduce) -> output GEMM.

typedef __attribute__((ext_vector_type(8))) __bf16 bf16x8;
typedef __attribute__((ext_vector_type(4))) float f32x4;
typedef unsigned short u16;

constexpr int BATCH  = 2;
constexpr int TSEQ   = 2048;
constexpr int DMODEL = 1024;
constexpr int NHEAD  = 16;
constexpr int DHEAD  = 64;
constexpr int MROWS  = BATCH * TSEQ;  // 4096

static __device__ __forceinline__ u16 f2bf(float f) {
  union { float f; unsigned int u; } v; v.f = f;
  unsigned int u = v.u;
  return (u16)((u + 0x7fffu + ((u >> 16) & 1u)) >> 16);
}

// async global->LDS, 16B per lane; lds base must be wave-uniform (HW adds lane*16)
static __device__ __forceinline__ void gload16(const void* g, void* l) {
  __builtin_amdgcn_global_load_lds(
      (const __attribute__((address_space(1))) void*)g,
      (__attribute__((address_space(3))) void*)l, 16, 0, 0);
}

__global__ __launch_bounds__(256) void cvt_multi(const float* __restrict__ s0,
                                                 const float* __restrict__ s1,
                                                 const float* __restrict__ s2,
                                                 const float* __restrict__ s3,
                                                 u16* __restrict__ d0, u16* __restrict__ d1,
                                                 u16* __restrict__ d2, u16* __restrict__ d3,
                                                 int n4) {
  const float* s; u16* d;
  switch (blockIdx.y) {
    case 0: s = s0; d = d0; break;
    case 1: s = s1; d = d1; break;
    case 2: s = s2; d = d2; break;
    default: s = s3; d = d3; break;
  }
  int i = blockIdx.x * 256 + threadIdx.x;
  if (i >= n4) return;
  float4 f = ((const float4*)s)[i];
  ushort4 o;
  o.x = f2bf(f.x); o.y = f2bf(f.y); o.z = f2bf(f.z); o.w = f2bf(f.w);
  ((ushort4*)d)[i] = o;
}

// ---------------- GEMM core (unchanged from r3) ----------------
template <typename Epi>
static __device__ __forceinline__ void gemm_body(const u16* __restrict__ X_,
                                                 const u16* __restrict__ W_,
                                                 const float* __restrict__ bias,
                                                 Epi epi) {
  __shared__ __align__(16) u16 As[2][4096];
  __shared__ __align__(16) u16 Bs[2][4096];
  const int lane = threadIdx.x & 63, wave = threadIdx.x >> 6;
  const int l16 = lane & 15, lk = lane >> 4;
  const int wm = wave >> 2, wn = wave & 3;
  const int row0 = blockIdx.x * 128, col0 = blockIdx.y * 128;
  constexpr int K = DMODEL;
  const u16* ga = X_ + (size_t)(row0 + wave * 16 + l16) * K + lk * 8;
  const u16* gb = W_ + (size_t)(col0 + wave * 16 + l16) * K + lk * 8;
  f32x4 acc[4][2];
#pragma unroll
  for (int mt = 0; mt < 4; ++mt)
#pragma unroll
    for (int nt = 0; nt < 2; ++nt) acc[mt][nt] = (f32x4){0.f, 0.f, 0.f, 0.f};
  gload16(ga, &As[0][wave * 512]);
  gload16(gb, &Bs[0][wave * 512]);
  __syncthreads();
  int buf = 0;
  for (int ks = 0; ks < K / 32; ++ks) {
    if (ks + 1 < K / 32) {
      gload16(ga + (ks + 1) * 32, &As[buf ^ 1][wave * 512]);
      gload16(gb + (ks + 1) * 32, &Bs[buf ^ 1][wave * 512]);
    }
    bf16x8 a[4], b[2];
#pragma unroll
    for (int mt = 0; mt < 4; ++mt)
      a[mt] = *(const bf16x8*)&As[buf][(wm * 4 + mt) * 512 + lane * 8];
#pragma unroll
    for (int nt = 0; nt < 2; ++nt)
      b[nt] = *(const bf16x8*)&Bs[buf][(wn * 2 + nt) * 512 + lane * 8];
#pragma unroll
    for (int mt = 0; mt < 4; ++mt)
#pragma unroll
      for (int nt = 0; nt < 2; ++nt)
        acc[mt][nt] =
            __builtin_amdgcn_mfma_f32_16x16x32_bf16(a[mt], b[nt], acc[mt][nt], 0, 0, 0);
    __syncthreads();
    buf ^= 1;
  }
#pragma unroll
  for (int mt = 0; mt < 4; ++mt)
#pragma unroll
    for (int nt = 0; nt < 2; ++nt)
#pragma unroll
      for (int r = 0; r < 4; ++r) {
        int m = row0 + wm * 64 + mt * 16 + lk * 4 + r;
        int n = col0 + wn * 32 + nt * 16 + l16;
        float v = acc[mt][nt][r] + bias[n];
        epi(m, n, v);
      }
}

// z: 0=Q (scaled by 1/8) , 1=K (both -> [B,H,T,dh]), 2=V (-> [B,H,dh,T])
__global__ __launch_bounds__(512) void gemm_qkv(
    const u16* __restrict__ xq, const u16* __restrict__ xk, const u16* __restrict__ xv,
    const u16* __restrict__ wq, const u16* __restrict__ wk, const u16* __restrict__ wv,
    const float* __restrict__ bq, const float* __restrict__ bk, const float* __restrict__ bv,
    u16* __restrict__ Qh, u16* __restrict__ Kh, u16* __restrict__ Vt) {
  const int z = blockIdx.z;
  const u16* X = z == 0 ? xq : (z == 1 ? xk : xv);
  const u16* W = z == 0 ? wq : (z == 1 ? wk : wv);
  const float* bias = z == 0 ? bq : (z == 1 ? bk : bv);
  u16* O01 = z == 0 ? Qh : Kh;
  gemm_body(X, W, bias, [&](int m, int n, float v) {
    int bb = m >> 11, t = m & (TSEQ - 1);
    int h = n >> 6, dd = n & (DHEAD - 1);
    if (z == 0) v *= 0.125f;  // fold 1/sqrt(dh) into Q
    if (z == 2)
      Vt[(((size_t)(bb * NHEAD + h)) * DHEAD + dd) * TSEQ + t] = f2bf(v);
    else
      O01[(((size_t)(bb * NHEAD + h)) * TSEQ + t) * DHEAD + dd] = f2bf(v);
  });
}

__global__ __launch_bounds__(512) void gemm_o(const u16* __restrict__ AO,
                                              const u16* __restrict__ wo,
                                              const float* __restrict__ bias,
                                              float* __restrict__ out) {
  gemm_body(AO, wo, bias,
            [&](int m, int n, float v) { out[(size_t)m * DMODEL + n] = v; });
}

// ---------------- flash attention ----------------
// 512 thr = 8 waves; block owns 128 q-rows (waves 0-3: rows q0..q0+63,
// waves 4-7: q0+64..q0+127), all sharing K/V LDS tiles (64-wide, dbuf,
// prefetched). Defer-max softmax (THR=8), per-lane partial sums reduced once
// at the end, masking only on each wave's diagonal K-block.
__global__ __launch_bounds__(512, 6) void flash_attn(const u16* __restrict__ Qh,
                                                     const u16* __restrict__ Kh,
                                                     const u16* __restrict__ Vt,
                                                     u16* __restrict__ AO) {
  const int lane = threadIdx.x & 63, wave = threadIdx.x >> 6;
  const int l16 = lane & 15, lk = lane >> 4;
  const int bh = blockIdx.x;
  const int qt = (gridDim.y - 1) - blockIdx.y;  // heavy-first
  const int q0 = qt * 128;
  const int b = bh >> 4, h = bh & 15;

  __shared__ __align__(16) u16 Kl[2][4096];
  __shared__ __align__(16) u16 Vl[2][4096];
  __shared__ __align__(16) u16 plds[8][16][72];

  const u16* Qb = Qh + (size_t)bh * TSEQ * DHEAD;
  const u16* Kb = Kh + (size_t)bh * TSEQ * DHEAD;
  const u16* Vb = Vt + (size_t)bh * DHEAD * TSEQ;

  bf16x8 qf[2];
  {
    const u16* qp = Qb + (size_t)(q0 + wave * 16 + l16) * DHEAD + lk * 8;
    qf[0] = *(const bf16x8*)(qp);
    qf[1] = *(const bf16x8*)(qp + 32);
  }

  float mrow[4], lsum[4];
  f32x4 acco[4];
#pragma unroll
  for (int r = 0; r < 4; ++r) { mrow[r] = -1e30f; lsum[r] = 0.f; }
#pragma unroll
  for (int dt = 0; dt < 4; ++dt) acco[dt] = (f32x4){0.f, 0.f, 0.f, 0.f};

  // staging: wave = site s (0..7): K rows (s>>1)*16+l16, dh slot (s&1)*4+lk;
  // V rows (dh) same pattern, t-offset (s&1)*32+lk*8. LDS dest linear per site.
  auto stage_kv = [&](int bufi, int kbase) {
    int trow = (wave >> 1) * 16 + l16;
    int dhs = (wave & 1) * 4 + lk;
    gload16(Kb + (size_t)(kbase + trow) * DHEAD + dhs * 8, &Kl[bufi][wave * 512]);
    gload16(Vb + (size_t)trow * TSEQ + kbase + dhs * 8, &Vl[bufi][wave * 512]);
  };

  const int nkb = 2 * qt + 2;
  const int kbdiag = 2 * qt + (wave >> 2);  // this wave's diagonal K-block
  stage_kv(0, 0);
  __syncthreads();
  int buf = 0;
  const int qrow_base = q0 + wave * 16 + 4 * lk;

  for (int kb = 0; kb < nkb; ++kb) {
    const int kbase = kb * 64;
    if (kb + 1 < nkb) stage_kv(buf ^ 1, kbase + 64);

    if (kb <= kbdiag) {
      f32x4 s[4];
#pragma unroll
      for (int nt = 0; nt < 4; ++nt) {
        bf16x8 k0f = *(const bf16x8*)&Kl[buf][nt * 1024 + lane * 8];
        bf16x8 k1f = *(const bf16x8*)&Kl[buf][nt * 1024 + 512 + lane * 8];
        f32x4 z = (f32x4){0.f, 0.f, 0.f, 0.f};
        z = __builtin_amdgcn_mfma_f32_16x16x32_bf16(qf[0], k0f, z, 0, 0, 0);
        z = __builtin_amdgcn_mfma_f32_16x16x32_bf16(qf[1], k1f, z, 0, 0, 0);
        s[nt] = z;
      }
      if (kb == kbdiag) {  // only the diagonal block needs masking
#pragma unroll
        for (int nt = 0; nt < 4; ++nt)
#pragma unroll
          for (int r = 0; r < 4; ++r) {
            int kcol = kbase + nt * 16 + l16;
            s[nt][r] = (kcol <= qrow_base + r) ? s[nt][r] : -1e30f;
          }
      }
      // defer-max: per-lane partial max; rescale only if any row exceeds m+8
      float pmax[4];
      bool need = false;
#pragma unroll
      for (int r = 0; r < 4; ++r) {
        pmax[r] = fmaxf(fmaxf(s[0][r], s[1][r]), fmaxf(s[2][r], s[3][r]));
        need |= (pmax[r] > mrow[r] + 8.f);
      }
      if (__any(need)) {
#pragma unroll
        for (int r = 0; r < 4; ++r) {
          float mx = pmax[r];
#pragma unroll
          for (int off = 1; off < 16; off <<= 1) mx = fmaxf(mx, __shfl_xor(mx, off, 16));
          float mnew = fmaxf(mrow[r], mx);
          float alpha = __expf(mrow[r] - mnew);
          lsum[r] *= alpha;
#pragma unroll
          for (int dt = 0; dt < 4; ++dt) acco[dt][r] *= alpha;
          mrow[r] = mnew;
        }
      }
#pragma unroll
      for (int r = 0; r < 4; ++r)
#pragma unroll
        for (int nt = 0; nt < 4; ++nt) {
          float p = __expf(s[nt][r] - mrow[r]);
          s[nt][r] = p;
          lsum[r] += p;
        }
      // P (D-layout) -> wave-private LDS -> A-fragment layout
#pragma unroll
      for (int nt = 0; nt < 4; ++nt)
#pragma unroll
        for (int r = 0; r < 4; ++r)
          plds[wave][4 * lk + r][nt * 16 + l16] = f2bf(s[nt][r]);
      bf16x8 pf0 = *(const bf16x8*)&plds[wave][l16][lk * 8];
      bf16x8 pf1 = *(const bf16x8*)&plds[wave][l16][32 + lk * 8];
#pragma unroll
      for (int dt = 0; dt < 4; ++dt) {
        bf16x8 v0 = *(const bf16x8*)&Vl[buf][dt * 1024 + lane * 8];
        bf16x8 v1 = *(const bf16x8*)&Vl[buf][dt * 1024 + 512 + lane * 8];
        acco[dt] = __builtin_amdgcn_mfma_f32_16x16x32_bf16(pf0, v0, acco[dt], 0, 0, 0);
        acco[dt] = __builtin_amdgcn_mfma_f32_16x16x32_bf16(pf1, v1, acco[dt], 0, 0, 0);
      }
    }
    __syncthreads();  // staged buf^1 ready; buf safe to overwrite next iter
    buf ^= 1;
  }

  // final 16-lane-group sum reduce, then write
#pragma unroll
  for (int r = 0; r < 4; ++r) {
    float t = lsum[r];
#pragma unroll
    for (int off = 1; off < 16; off <<= 1) t += __shfl_xor(t, off, 16);
    lsum[r] = 1.f / t;
  }
#pragma unroll
  for (int dt = 0; dt < 4; ++dt)
#pragma unroll
    for (int r = 0; r < 4; ++r) {
      int t = qrow_base + r;
      int col = h * DHEAD + dt * 16 + l16;
      AO[((size_t)(b * TSEQ + t)) * DMODEL + col] = f2bf(acco[dt][r] * lsum[r]);
    }
}

extern "C" void kernel_launch(void* const* d_in, const int* in_sizes, int n_in,
                              void* d_out, int out_size, void* d_ws, size_t ws_size,
                              hipStream_t stream) {
  const float* x_q = (const float*)d_in[0];
  const float* x_k = (const float*)d_in[1];
  const float* x_v = (const float*)d_in[2];
  const float* Wq = (const float*)d_in[4];
  const float* bq = (const float*)d_in[5];
  const float* Wk = (const float*)d_in[6];
  const float* bk = (const float*)d_in[7];
  const float* Wv = (const float*)d_in[8];
  const float* bv = (const float*)d_in[9];
  const float* Wo = (const float*)d_in[10];
  const float* bo = (const float*)d_in[11];

  const size_t nx = (size_t)MROWS * DMODEL;
  const size_t nw = (size_t)DMODEL * DMODEL;
  u16* ws   = (u16*)d_ws;
  u16* xq_b = ws;
  u16* xk_b = xq_b + nx;
  u16* xv_b = xk_b + nx;
  u16* wq_b = xv_b + nx;
  u16* wk_b = wq_b + nw;
  u16* wv_b = wk_b + nw;
  u16* wo_b = wv_b + nw;
  u16* Qh   = wo_b + nw;
  u16* Kh   = Qh + nx;
  u16* Vt   = Kh + nx;
  u16* AO   = Vt + nx;  // total 64 MiB

  const int n4x = (int)(nx / 4), n4w = (int)(nw / 4);
  cvt_multi<<<dim3((n4x + 255) / 256, 3), 256, 0, stream>>>(
      x_q, x_k, x_v, nullptr, xq_b, xk_b, xv_b, nullptr, n4x);
  cvt_multi<<<dim3((n4w + 255) / 256, 4), 256, 0, stream>>>(
      Wq, Wk, Wv, Wo, wq_b, wk_b, wv_b, wo_b, n4w);

  gemm_qkv<<<dim3(MROWS / 128, DMODEL / 128, 3), 512, 0, stream>>>(
      xq_b, xk_b, xv_b, wq_b, wk_b, wv_b, bq, bk, bv, Qh, Kh, Vt);

  flash_attn<<<dim3(BATCH * NHEAD, TSEQ / 128), 512, 0, stream>>>(Qh, Kh, Vt, AO);

  gemm_o<<<dim3(MROWS / 128, DMODEL / 128), 512, 0, stream>>>(AO, wo_b, bo, (float*)d_out);
}